// Round 1
// baseline (156.936 us; speedup 1.0000x reference)
//
#include <hip/hip_runtime.h>
#include <math.h>

#define BB 2
#define LL 1024
#define DD 512
#define HH 8
#define DHD 64
#define QQ 64
#define NCC 16

// ---------------------------------------------------------------------------
// Kernel 1: fused 3x GEMM  pre = x @ W^T + b  for W_A/W_B/W_C, with
// activation: logA = logsigmoid(preA), Bf = preB, Cf = preC.
// M=2048 tokens, N=512 outputs, K=512. 64x64 tile, 256 thr, 4x4/thread.
// ---------------------------------------------------------------------------
__global__ __launch_bounds__(256) void gemm3_act(
    const float* __restrict__ x,
    const float* __restrict__ Wa, const float* __restrict__ ba,
    const float* __restrict__ Wb, const float* __restrict__ bb,
    const float* __restrict__ Wc, const float* __restrict__ bc,
    float* __restrict__ logA, float* __restrict__ Bf, float* __restrict__ Cf)
{
    __shared__ float Xs[32][68];   // [k][row]
    __shared__ float Was[32][68];
    __shared__ float Wbs[32][68];
    __shared__ float Wcs[32][68];

    const int bm = blockIdx.x >> 3;   // 32 M-tiles
    const int bn = blockIdx.x & 7;    // 8 N-tiles
    const int n0 = bm << 6;
    const int o0 = bn << 6;
    const int t  = threadIdx.x;
    const int ty4 = (t >> 4) << 2;
    const int tx4 = (t & 15) << 2;
    const int lr = t >> 3;            // 0..31
    const int lc = (t & 7) << 2;      // 0..28

    float accA[4][4] = {};
    float accB[4][4] = {};
    float accC[4][4] = {};

    for (int kt = 0; kt < DD; kt += 32) {
        #pragma unroll
        for (int half = 0; half < 2; ++half) {
            const int row = lr + (half << 5);
            float4 v;
            v = *(const float4*)&x[(size_t)(n0 + row) * DD + kt + lc];
            Xs[lc+0][row] = v.x; Xs[lc+1][row] = v.y; Xs[lc+2][row] = v.z; Xs[lc+3][row] = v.w;
            v = *(const float4*)&Wa[(size_t)(o0 + row) * DD + kt + lc];
            Was[lc+0][row] = v.x; Was[lc+1][row] = v.y; Was[lc+2][row] = v.z; Was[lc+3][row] = v.w;
            v = *(const float4*)&Wb[(size_t)(o0 + row) * DD + kt + lc];
            Wbs[lc+0][row] = v.x; Wbs[lc+1][row] = v.y; Wbs[lc+2][row] = v.z; Wbs[lc+3][row] = v.w;
            v = *(const float4*)&Wc[(size_t)(o0 + row) * DD + kt + lc];
            Wcs[lc+0][row] = v.x; Wcs[lc+1][row] = v.y; Wcs[lc+2][row] = v.z; Wcs[lc+3][row] = v.w;
        }
        __syncthreads();
        #pragma unroll 8
        for (int kk = 0; kk < 32; ++kk) {
            const float4 av = *(const float4*)&Xs[kk][ty4];
            const float4 pa = *(const float4*)&Was[kk][tx4];
            const float4 pb = *(const float4*)&Wbs[kk][tx4];
            const float4 pc = *(const float4*)&Wcs[kk][tx4];
            const float a[4]  = {av.x, av.y, av.z, av.w};
            const float wa[4] = {pa.x, pa.y, pa.z, pa.w};
            const float wb[4] = {pb.x, pb.y, pb.z, pb.w};
            const float wc[4] = {pc.x, pc.y, pc.z, pc.w};
            #pragma unroll
            for (int i = 0; i < 4; ++i) {
                #pragma unroll
                for (int j = 0; j < 4; ++j) {
                    accA[i][j] += a[i] * wa[j];
                    accB[i][j] += a[i] * wb[j];
                    accC[i][j] += a[i] * wc[j];
                }
            }
        }
        __syncthreads();
    }

    #pragma unroll
    for (int i = 0; i < 4; ++i) {
        const int nrow = n0 + ty4 + i;
        const size_t rb = (size_t)nrow * DD + o0 + tx4;
        float va[4], vb[4], vc[4];
        #pragma unroll
        for (int j = 0; j < 4; ++j) {
            const int o = o0 + tx4 + j;
            const float za = accA[i][j] + ba[o];
            // stable logsigmoid(z) = min(z,0) - log1p(exp(-|z|))
            va[j] = fminf(za, 0.f) - log1pf(__expf(-fabsf(za)));
            vb[j] = accB[i][j] + bb[o];
            vc[j] = accC[i][j] + bc[o];
        }
        *(float4*)&logA[rb] = make_float4(va[0], va[1], va[2], va[3]);
        *(float4*)&Bf[rb]   = make_float4(vb[0], vb[1], vb[2], vb[3]);
        *(float4*)&Cf[rb]   = make_float4(vc[0], vc[1], vc[2], vc[3]);
    }
}

// ---------------------------------------------------------------------------
// Kernel 2a: per-chunk sums of logA. block = (bh, chunk), 64 threads (d).
// ---------------------------------------------------------------------------
__global__ __launch_bounds__(64) void chunk_sums(
    const float* __restrict__ logA, float* __restrict__ csum)
{
    const int blk = blockIdx.x;       // bh*16 + c
    const int bh = blk >> 4, c = blk & 15;
    const int b = bh >> 3, h = bh & 7;
    const int d = threadIdx.x;
    const size_t base = (size_t)(b * LL + c * QQ) * DD + h * DHD + d;
    float s = 0.f;
    #pragma unroll 8
    for (int i = 0; i < QQ; ++i) s += logA[base + (size_t)i * DD];
    csum[(size_t)blk * DHD + d] = s;
}

// ---------------------------------------------------------------------------
// Kernel 2b: per-chunk rescan -> Sloc (within-chunk cumsum), qf, kf, coff.
// qf = C*exp(prefix_before), kf = B*exp(chunktotal - prefix_after).
// coff[bh][m] = global cumsum through end of chunk m-1 (m = 0..16).
// ---------------------------------------------------------------------------
__global__ __launch_bounds__(64) void scan_chunk(
    const float* __restrict__ logA, const float* __restrict__ Bf,
    const float* __restrict__ Cf, const float* __restrict__ csum,
    float* __restrict__ Sloc, float* __restrict__ qf, float* __restrict__ kf,
    float* __restrict__ coff)
{
    const int blk = blockIdx.x;       // bh*16 + c
    const int bh = blk >> 4, c = blk & 15;
    const int b = bh >> 3, h = bh & 7;
    const int d = threadIdx.x;

    const size_t cs0 = ((size_t)bh << 4) * DHD + d;
    float off = 0.f;
    for (int cc = 0; cc < c; ++cc) off += csum[cs0 + (size_t)cc * DHD];
    const float tot = csum[cs0 + (size_t)c * DHD];
    coff[((size_t)bh * 17 + c) * DHD + d] = off;
    if (c == NCC - 1) coff[((size_t)bh * 17 + 16) * DHD + d] = off + tot;

    const size_t gbase = (size_t)(b * LL + c * QQ) * DD + h * DHD + d;
    const size_t hbase = ((size_t)bh * LL + c * QQ) * DHD + d;
    float run = 0.f;
    #pragma unroll 4
    for (int i = 0; i < QQ; ++i) {
        const size_t gi = gbase + (size_t)i * DD;
        const float la = logA[gi];
        const float cv = Cf[gi];
        const float bv = Bf[gi];
        qf[hbase + (size_t)i * DHD] = cv * __expf(run);   // exp(Sm1 - Eprev)
        run += la;
        Sloc[hbase + (size_t)i * DHD] = run;
        kf[hbase + (size_t)i * DHD] = bv * __expf(tot - run); // exp(E - S)
    }
}

// ---------------------------------------------------------------------------
// Kernel 3: T assembly. One block per (bh, m, n) 64x64 tile.
//  n > m : zeros.  n < m : qf_m @ diag(exp(coff[m]-coff[n+1])) @ kf_n^T.
//  n == m: per-element masked  sum_d C_q exp(Sloc_{q-1}-Sloc_k) B_k  (diag w=1).
// ---------------------------------------------------------------------------
__global__ __launch_bounds__(256) void t_kernel(
    const float* __restrict__ qf, const float* __restrict__ kf,
    const float* __restrict__ Sloc, const float* __restrict__ coff,
    const float* __restrict__ Bf, const float* __restrict__ Cf,
    float* __restrict__ out)
{
    __shared__ float smA[DHD][68];   // qsT / csT   [d][row]
    __shared__ float smB[DHD][68];   // ksT / bsT
    __shared__ float smC[DHD][68];   // slT (diag only)
    __shared__ float dv[DHD];

    const int blk = blockIdx.x;
    const int bh = blk >> 8;
    const int mn = blk & 255;
    const int m = mn >> 4, n = mn & 15;
    const int b = bh >> 3, h = bh & 7;
    const int t = threadIdx.x;
    const int q0 = ((t >> 4) & 15) << 2;
    const int k0 = (t & 15) << 2;

    const size_t outrow0 = ((size_t)bh * LL + (size_t)m * QQ) * LL + (size_t)n * QQ;

    if (n > m) {
        const float4 z = make_float4(0.f, 0.f, 0.f, 0.f);
        #pragma unroll
        for (int i = 0; i < 4; ++i)
            *(float4*)&out[outrow0 + (size_t)(q0 + i) * LL + k0] = z;
        return;
    }

    const int r  = t >> 4;            // 0..15 (load row group)
    const int dg = (t & 15) << 2;     // 0..60 (load d group)

    if (n < m) {
        if (t < DHD) {
            const size_t cb = (size_t)bh * 17 * DHD + t;
            dv[t] = __expf(coff[cb + (size_t)m * DHD] - coff[cb + (size_t)(n + 1) * DHD]);
        }
        __syncthreads();
        const size_t qb = ((size_t)bh * LL + (size_t)m * QQ) * DHD;
        const size_t kb = ((size_t)bh * LL + (size_t)n * QQ) * DHD;
        const float s0 = dv[dg+0], s1 = dv[dg+1], s2 = dv[dg+2], s3 = dv[dg+3];
        #pragma unroll
        for (int rr = 0; rr < 64; rr += 16) {
            const int row = r + rr;
            float4 v = *(const float4*)&qf[qb + (size_t)row * DHD + dg];
            smA[dg+0][row] = v.x; smA[dg+1][row] = v.y; smA[dg+2][row] = v.z; smA[dg+3][row] = v.w;
            float4 w = *(const float4*)&kf[kb + (size_t)row * DHD + dg];
            smB[dg+0][row] = w.x*s0; smB[dg+1][row] = w.y*s1; smB[dg+2][row] = w.z*s2; smB[dg+3][row] = w.w*s3;
        }
        __syncthreads();
        float acc[4][4] = {};
        #pragma unroll 4
        for (int d = 0; d < DHD; ++d) {
            const float4 av = *(const float4*)&smA[d][q0];
            const float4 bv = *(const float4*)&smB[d][k0];
            const float a0 = av.x, a1 = av.y, a2 = av.z, a3 = av.w;
            const float c0 = bv.x, c1 = bv.y, c2 = bv.z, c3 = bv.w;
            acc[0][0] += a0*c0; acc[0][1] += a0*c1; acc[0][2] += a0*c2; acc[0][3] += a0*c3;
            acc[1][0] += a1*c0; acc[1][1] += a1*c1; acc[1][2] += a1*c2; acc[1][3] += a1*c3;
            acc[2][0] += a2*c0; acc[2][1] += a2*c1; acc[2][2] += a2*c2; acc[2][3] += a2*c3;
            acc[3][0] += a3*c0; acc[3][1] += a3*c1; acc[3][2] += a3*c2; acc[3][3] += a3*c3;
        }
        #pragma unroll
        for (int i = 0; i < 4; ++i)
            *(float4*)&out[outrow0 + (size_t)(q0 + i) * LL + k0] =
                make_float4(acc[i][0], acc[i][1], acc[i][2], acc[i][3]);
        return;
    }

    // ---- diagonal chunk ----
    {
        const size_t ab = (size_t)(b * LL + m * QQ) * DD + h * DHD;
        const size_t sb = ((size_t)bh * LL + (size_t)m * QQ) * DHD;
        #pragma unroll
        for (int rr = 0; rr < 64; rr += 16) {
            const int row = r + rr;
            float4 cv = *(const float4*)&Cf[ab + (size_t)row * DD + dg];
            smA[dg+0][row] = cv.x; smA[dg+1][row] = cv.y; smA[dg+2][row] = cv.z; smA[dg+3][row] = cv.w;
            float4 bv = *(const float4*)&Bf[ab + (size_t)row * DD + dg];
            smB[dg+0][row] = bv.x; smB[dg+1][row] = bv.y; smB[dg+2][row] = bv.z; smB[dg+3][row] = bv.w;
            float4 sv = *(const float4*)&Sloc[sb + (size_t)row * DHD + dg];
            smC[dg+0][row] = sv.x; smC[dg+1][row] = sv.y; smC[dg+2][row] = sv.z; smC[dg+3][row] = sv.w;
        }
        __syncthreads();
        float acc[4][4] = {};
        if (q0 + 3 >= k0) {   // skip fully-upper 4x4 sub-tiles
            #pragma unroll 2
            for (int d = 0; d < DHD; ++d) {
                const float4 cq = *(const float4*)&smA[d][q0];
                const float4 bk = *(const float4*)&smB[d][k0];
                const float4 sk = *(const float4*)&smC[d][k0];
                const float cqa[4] = {cq.x, cq.y, cq.z, cq.w};
                const float bka[4] = {bk.x, bk.y, bk.z, bk.w};
                const float ska[4] = {sk.x, sk.y, sk.z, sk.w};
                float s1a[4];
                #pragma unroll
                for (int i = 0; i < 4; ++i) {
                    const int qi = q0 + i;
                    const int qm = (qi > 0) ? (qi - 1) : 0;
                    s1a[i] = (qi == 0) ? 0.f : smC[d][qm];   // Sloc_{q-1}, 0 at q=0
                }
                #pragma unroll
                for (int i = 0; i < 4; ++i) {
                    #pragma unroll
                    for (int j = 0; j < 4; ++j) {
                        const int qi = q0 + i, kj = k0 + j;
                        const float wgt = (qi > kj) ? __expf(s1a[i] - ska[j])
                                                    : ((qi == kj) ? 1.f : 0.f);
                        acc[i][j] += cqa[i] * wgt * bka[j];
                    }
                }
            }
        }
        #pragma unroll
        for (int i = 0; i < 4; ++i)
            *(float4*)&out[outrow0 + (size_t)(q0 + i) * LL + k0] =
                make_float4(acc[i][0], acc[i][1], acc[i][2], acc[i][3]);
    }
}

// ---------------------------------------------------------------------------
extern "C" void kernel_launch(void* const* d_in, const int* in_sizes, int n_in,
                              void* d_out, int out_size, void* d_ws, size_t ws_size,
                              hipStream_t stream) {
    const float* x  = (const float*)d_in[0];
    const float* Wa = (const float*)d_in[1];
    const float* ba = (const float*)d_in[2];
    const float* Wb = (const float*)d_in[3];
    const float* bb = (const float*)d_in[4];
    const float* Wc = (const float*)d_in[5];
    const float* bc = (const float*)d_in[6];
    float* out = (float*)d_out;
    float* ws  = (float*)d_ws;

    const size_t NBLD = (size_t)BB * LL * DD;   // 1,048,576
    float* logA = ws;
    float* Bf   = ws + 1 * NBLD;
    float* Cf   = ws + 2 * NBLD;
    float* Sl   = ws + 3 * NBLD;
    float* qf   = ws + 4 * NBLD;
    float* kf   = ws + 5 * NBLD;
    float* coff = ws + 6 * NBLD;                        // 16*17*64 floats
    float* csum = coff + (size_t)BB * HH * 17 * DHD;    // 256*64 floats

    gemm3_act<<<256, 256, 0, stream>>>(x, Wa, ba, Wb, bb, Wc, bc, logA, Bf, Cf);
    chunk_sums<<<BB * HH * NCC, 64, 0, stream>>>(logA, csum);
    scan_chunk<<<BB * HH * NCC, 64, 0, stream>>>(logA, Bf, Cf, csum, Sl, qf, kf, coff);
    t_kernel<<<BB * HH * NCC * NCC, 256, 0, stream>>>(qf, kf, Sl, coff, Bf, Cf, out);
}

// Round 2
// 133.194 us; speedup vs baseline: 1.1782x; 1.1782x over previous
//
#include <hip/hip_runtime.h>
#include <math.h>

#define BB 2
#define LL 1024
#define DD 512
#define HH 8
#define DHD 64
#define QQ 64
#define NCC 16

// ---------------------------------------------------------------------------
// Kernel 1: one GEMM per block-group.  w = blockIdx>>8 selects W_A/W_B/W_C.
// out = x @ W^T + b ; w==0 additionally applies logsigmoid.
// M=2048, N=512, K=512. 64x64 tile, 256 thr, 4x4/thread. 768 blocks.
// ---------------------------------------------------------------------------
__global__ __launch_bounds__(256) void gemm3_act_v2(
    const float* __restrict__ x,
    const float* __restrict__ Wa, const float* __restrict__ ba,
    const float* __restrict__ Wb, const float* __restrict__ bb,
    const float* __restrict__ Wc, const float* __restrict__ bc,
    float* __restrict__ logA, float* __restrict__ Bf, float* __restrict__ Cf)
{
    __shared__ float Xs[32][65];   // [k][row], pad 65 (65 mod 32 == 1 -> 2-way max)
    __shared__ float Ws[32][65];

    const int wsel = blockIdx.x >> 8;
    const int tile = blockIdx.x & 255;
    const int bm = tile >> 3;         // 32 M-tiles
    const int bn = tile & 7;          // 8 N-tiles
    const int n0 = bm << 6;
    const int o0 = bn << 6;
    const int t  = threadIdx.x;
    const int ty4 = (t >> 4) << 2;
    const int tx4 = (t & 15) << 2;
    const int lr = t >> 3;            // 0..31
    const int lc = (t & 7) << 2;      // 0..28

    const float* __restrict__ W    = (wsel == 0) ? Wa : ((wsel == 1) ? Wb : Wc);
    const float* __restrict__ bias = (wsel == 0) ? ba : ((wsel == 1) ? bb : bc);

    float acc[4][4] = {};

    for (int kt = 0; kt < DD; kt += 32) {
        #pragma unroll
        for (int half = 0; half < 2; ++half) {
            const int row = lr + (half << 5);
            float4 v = *(const float4*)&x[(size_t)(n0 + row) * DD + kt + lc];
            Xs[lc+0][row] = v.x; Xs[lc+1][row] = v.y; Xs[lc+2][row] = v.z; Xs[lc+3][row] = v.w;
            float4 w = *(const float4*)&W[(size_t)(o0 + row) * DD + kt + lc];
            Ws[lc+0][row] = w.x; Ws[lc+1][row] = w.y; Ws[lc+2][row] = w.z; Ws[lc+3][row] = w.w;
        }
        __syncthreads();
        #pragma unroll 8
        for (int kk = 0; kk < 32; ++kk) {
            const float4 av = *(const float4*)&Xs[kk][ty4];
            const float4 wv = *(const float4*)&Ws[kk][tx4];
            const float a[4]  = {av.x, av.y, av.z, av.w};
            const float b[4]  = {wv.x, wv.y, wv.z, wv.w};
            #pragma unroll
            for (int i = 0; i < 4; ++i)
                #pragma unroll
                for (int j = 0; j < 4; ++j)
                    acc[i][j] += a[i] * b[j];
        }
        __syncthreads();
    }

    const float4 bv4 = *(const float4*)&bias[o0 + tx4];
    const float bb4[4] = {bv4.x, bv4.y, bv4.z, bv4.w};
    #pragma unroll
    for (int i = 0; i < 4; ++i) {
        const size_t rb = (size_t)(n0 + ty4 + i) * DD + o0 + tx4;
        float v[4];
        #pragma unroll
        for (int j = 0; j < 4; ++j) v[j] = acc[i][j] + bb4[j];
        if (wsel == 0) {
            #pragma unroll
            for (int j = 0; j < 4; ++j)
                v[j] = fminf(v[j], 0.f) - log1pf(__expf(-fabsf(v[j])));
            *(float4*)&logA[rb] = make_float4(v[0], v[1], v[2], v[3]);
        } else if (wsel == 1) {
            *(float4*)&Bf[rb] = make_float4(v[0], v[1], v[2], v[3]);
        } else {
            *(float4*)&Cf[rb] = make_float4(v[0], v[1], v[2], v[3]);
        }
    }
}

// ---------------------------------------------------------------------------
// Kernel 2a: per-chunk sums of logA. block=(bh,c), 256 thr: wave w sums 16 rows.
// ---------------------------------------------------------------------------
__global__ __launch_bounds__(256) void chunk_sums256(
    const float* __restrict__ logA, float* __restrict__ csum)
{
    __shared__ float part[4][DHD];
    const int blk = blockIdx.x;       // bh*16 + c
    const int bh = blk >> 4, c = blk & 15;
    const int b = bh >> 3, h = bh & 7;
    const int t = threadIdx.x;
    const int d = t & 63, w = t >> 6;
    const size_t base = (size_t)(b * LL + c * QQ + w * 16) * DD + h * DHD + d;
    float s = 0.f;
    #pragma unroll 4
    for (int i = 0; i < 16; ++i) s += logA[base + (size_t)i * DD];
    part[w][d] = s;
    __syncthreads();
    if (t < DHD)
        csum[(size_t)blk * DHD + t] = part[0][t] + part[1][t] + part[2][t] + part[3][t];
}

// ---------------------------------------------------------------------------
// Kernel 2b: scan. block=(bh,c), 256 thr = 4 waves x 16 rows each.
// qf = C*exp(local prefix), kf = B*exp(tot - local cumsum), Sloc, coff.
// ---------------------------------------------------------------------------
__global__ __launch_bounds__(256) void scan256(
    const float* __restrict__ logA, const float* __restrict__ Bf,
    const float* __restrict__ Cf, const float* __restrict__ csum,
    float* __restrict__ Sloc, float* __restrict__ qf, float* __restrict__ kf,
    float* __restrict__ coff)
{
    __shared__ float part[4][DHD];
    const int blk = blockIdx.x;
    const int bh = blk >> 4, c = blk & 15;
    const int b = bh >> 3, h = bh & 7;
    const int t = threadIdx.x;
    const int d = t & 63, w = t >> 6;

    const size_t gbase = (size_t)(b * LL + c * QQ + w * 16) * DD + h * DHD + d;
    float ps = 0.f;
    #pragma unroll 4
    for (int i = 0; i < 16; ++i) ps += logA[gbase + (size_t)i * DD];
    part[w][d] = ps;
    __syncthreads();

    const size_t cs0 = ((size_t)bh << 4) * DHD + d;
    float off = 0.f;
    for (int cc = 0; cc < c; ++cc) off += csum[cs0 + (size_t)cc * DHD];
    const float tot = part[0][d] + part[1][d] + part[2][d] + part[3][d];
    if (t < DHD) {
        coff[((size_t)bh * 17 + c) * DHD + t] = off;
        if (c == NCC - 1) coff[((size_t)bh * 17 + 16) * DHD + t] = off + tot;
    }

    float run = 0.f;
    for (int ww = 0; ww < 4; ++ww) if (ww < w) run += part[ww][d];

    const size_t hbase = ((size_t)bh * LL + c * QQ + w * 16) * DHD + d;
    #pragma unroll 4
    for (int i = 0; i < 16; ++i) {
        const size_t gi = gbase + (size_t)i * DD;
        const float la = logA[gi];
        const float cv = Cf[gi];
        const float bv = Bf[gi];
        qf[hbase + (size_t)i * DHD] = cv * __expf(run);       // exp(Sm1 - Eprev)
        run += la;
        Sloc[hbase + (size_t)i * DHD] = run;
        kf[hbase + (size_t)i * DHD] = bv * __expf(tot - run); // exp(E - S)
    }
}

// ---------------------------------------------------------------------------
// Kernel 3a: zero-fill of strict-upper 64x64 tiles. 16 bh x 120 tiles.
// ---------------------------------------------------------------------------
__global__ __launch_bounds__(256) void zero_upper(float* __restrict__ out)
{
    const int bid = blockIdx.x;
    const int bh = bid / 120;
    const int idx = bid - bh * 120;
    int a = (int)((1.0f + sqrtf(1.0f + 8.0f * (float)idx)) * 0.5f);
    if (a * (a - 1) / 2 > idx) --a;
    else if ((a + 1) * a / 2 <= idx) ++a;
    const int bsm = a;                 // lower pair (a,b), a>b -> upper (m,n)=(b,a)
    const int bsn = idx - a * (a - 1) / 2;
    const int m = bsn, n = bsm;        // n > m

    const size_t base = ((size_t)bh * LL + (size_t)m * QQ) * LL + (size_t)n * QQ;
    const int t = threadIdx.x;
    const float4 z = make_float4(0.f, 0.f, 0.f, 0.f);
    #pragma unroll
    for (int j = 0; j < 4; ++j) {
        const int f = t + (j << 8);        // float4 index 0..1023
        const int row = f >> 4;
        const int col = (f & 15) << 2;
        *(float4*)&out[base + (size_t)row * LL + col] = z;
    }
}

// ---------------------------------------------------------------------------
// Kernel 3b: off-diagonal tiles: qf_m @ diag(exp(coff[m]-coff[n+1])) @ kf_n^T.
// 16 bh x 120 lower tiles. LDS 2x[64][65] -> 4 blocks/CU.
// ---------------------------------------------------------------------------
__global__ __launch_bounds__(256) void offdiag_kernel(
    const float* __restrict__ qf, const float* __restrict__ kf,
    const float* __restrict__ coff, float* __restrict__ out)
{
    __shared__ float smA[DHD][65];   // qf^T  [d][row]
    __shared__ float smB[DHD][65];   // kf^T * dv
    __shared__ float dv[DHD];

    const int bid = blockIdx.x;
    const int bh = bid / 120;
    const int idx = bid - bh * 120;
    int m = (int)((1.0f + sqrtf(1.0f + 8.0f * (float)idx)) * 0.5f);
    if (m * (m - 1) / 2 > idx) --m;
    else if ((m + 1) * m / 2 <= idx) ++m;
    const int n = idx - m * (m - 1) / 2;   // n < m

    const int t = threadIdx.x;
    const int q0 = ((t >> 4) & 15) << 2;
    const int k0 = (t & 15) << 2;
    const int r  = t >> 4;            // 0..15
    const int dg = (t & 15) << 2;     // 0..60

    if (t < DHD) {
        const size_t cb = (size_t)bh * 17 * DHD + t;
        dv[t] = __expf(coff[cb + (size_t)m * DHD] - coff[cb + (size_t)(n + 1) * DHD]);
    }
    __syncthreads();

    const size_t qb = ((size_t)bh * LL + (size_t)m * QQ) * DHD;
    const size_t kb = ((size_t)bh * LL + (size_t)n * QQ) * DHD;
    const float4 sv = *(const float4*)&dv[dg];
    #pragma unroll
    for (int rr = 0; rr < 64; rr += 16) {
        const int row = r + rr;
        float4 v = *(const float4*)&qf[qb + (size_t)row * DHD + dg];
        smA[dg+0][row] = v.x; smA[dg+1][row] = v.y; smA[dg+2][row] = v.z; smA[dg+3][row] = v.w;
        float4 w = *(const float4*)&kf[kb + (size_t)row * DHD + dg];
        smB[dg+0][row] = w.x*sv.x; smB[dg+1][row] = w.y*sv.y; smB[dg+2][row] = w.z*sv.z; smB[dg+3][row] = w.w*sv.w;
    }
    __syncthreads();

    float acc[4][4] = {};
    #pragma unroll 4
    for (int d = 0; d < DHD; ++d) {
        const float4 av = *(const float4*)&smA[d][q0];
        const float4 bv = *(const float4*)&smB[d][k0];
        acc[0][0] += av.x*bv.x; acc[0][1] += av.x*bv.y; acc[0][2] += av.x*bv.z; acc[0][3] += av.x*bv.w;
        acc[1][0] += av.y*bv.x; acc[1][1] += av.y*bv.y; acc[1][2] += av.y*bv.z; acc[1][3] += av.y*bv.w;
        acc[2][0] += av.z*bv.x; acc[2][1] += av.z*bv.y; acc[2][2] += av.z*bv.z; acc[2][3] += av.z*bv.w;
        acc[3][0] += av.w*bv.x; acc[3][1] += av.w*bv.y; acc[3][2] += av.w*bv.z; acc[3][3] += av.w*bv.w;
    }

    const size_t outrow0 = ((size_t)bh * LL + (size_t)m * QQ) * LL + (size_t)n * QQ;
    #pragma unroll
    for (int i = 0; i < 4; ++i)
        *(float4*)&out[outrow0 + (size_t)(q0 + i) * LL + k0] =
            make_float4(acc[i][0], acc[i][1], acc[i][2], acc[i][3]);
}

// ---------------------------------------------------------------------------
// Kernel 3c: diagonal tiles: masked elementwise  C_q exp(Sloc_{q-1}-Sloc_k) B_k.
// 256 blocks (bh, m).
// ---------------------------------------------------------------------------
__global__ __launch_bounds__(256) void diag_kernel(
    const float* __restrict__ Sloc, const float* __restrict__ Bf,
    const float* __restrict__ Cf, float* __restrict__ out)
{
    __shared__ float smA[DHD][65];   // C^T  [d][row]
    __shared__ float smB[DHD][65];   // B^T
    __shared__ float smC[DHD][65];   // Sloc^T

    const int blk = blockIdx.x;      // bh*16 + m
    const int bh = blk >> 4, m = blk & 15;
    const int b = bh >> 3, h = bh & 7;
    const int t = threadIdx.x;
    const int q0 = ((t >> 4) & 15) << 2;
    const int k0 = (t & 15) << 2;
    const int r  = t >> 4;
    const int dg = (t & 15) << 2;

    const size_t ab = (size_t)(b * LL + m * QQ) * DD + h * DHD;
    const size_t sb = ((size_t)bh * LL + (size_t)m * QQ) * DHD;
    #pragma unroll
    for (int rr = 0; rr < 64; rr += 16) {
        const int row = r + rr;
        float4 cv = *(const float4*)&Cf[ab + (size_t)row * DD + dg];
        smA[dg+0][row] = cv.x; smA[dg+1][row] = cv.y; smA[dg+2][row] = cv.z; smA[dg+3][row] = cv.w;
        float4 bv = *(const float4*)&Bf[ab + (size_t)row * DD + dg];
        smB[dg+0][row] = bv.x; smB[dg+1][row] = bv.y; smB[dg+2][row] = bv.z; smB[dg+3][row] = bv.w;
        float4 sv = *(const float4*)&Sloc[sb + (size_t)row * DHD + dg];
        smC[dg+0][row] = sv.x; smC[dg+1][row] = sv.y; smC[dg+2][row] = sv.z; smC[dg+3][row] = sv.w;
    }
    __syncthreads();

    float acc[4][4] = {};
    if (q0 + 3 >= k0) {
        #pragma unroll 2
        for (int d = 0; d < DHD; ++d) {
            const float4 cq = *(const float4*)&smA[d][q0];
            const float4 bk = *(const float4*)&smB[d][k0];
            const float4 sk = *(const float4*)&smC[d][k0];
            const float cqa[4] = {cq.x, cq.y, cq.z, cq.w};
            const float bka[4] = {bk.x, bk.y, bk.z, bk.w};
            const float ska[4] = {sk.x, sk.y, sk.z, sk.w};
            float s1a[4];
            #pragma unroll
            for (int i = 0; i < 4; ++i) {
                const int qi = q0 + i;
                s1a[i] = (qi == 0) ? 0.f : smC[d][qi - 1];
            }
            #pragma unroll
            for (int i = 0; i < 4; ++i) {
                #pragma unroll
                for (int j = 0; j < 4; ++j) {
                    const int qi = q0 + i, kj = k0 + j;
                    const float wgt = (qi > kj) ? __expf(s1a[i] - ska[j])
                                                : ((qi == kj) ? 1.f : 0.f);
                    acc[i][j] += cqa[i] * wgt * bka[j];
                }
            }
        }
    }
    const size_t outrow0 = ((size_t)bh * LL + (size_t)m * QQ) * LL + (size_t)m * QQ;
    #pragma unroll
    for (int i = 0; i < 4; ++i)
        *(float4*)&out[outrow0 + (size_t)(q0 + i) * LL + k0] =
            make_float4(acc[i][0], acc[i][1], acc[i][2], acc[i][3]);
}

// ---------------------------------------------------------------------------
extern "C" void kernel_launch(void* const* d_in, const int* in_sizes, int n_in,
                              void* d_out, int out_size, void* d_ws, size_t ws_size,
                              hipStream_t stream) {
    const float* x  = (const float*)d_in[0];
    const float* Wa = (const float*)d_in[1];
    const float* ba = (const float*)d_in[2];
    const float* Wb = (const float*)d_in[3];
    const float* bb = (const float*)d_in[4];
    const float* Wc = (const float*)d_in[5];
    const float* bc = (const float*)d_in[6];
    float* out = (float*)d_out;
    float* ws  = (float*)d_ws;

    const size_t NBLD = (size_t)BB * LL * DD;   // 1,048,576
    float* logA = ws;
    float* Bf   = ws + 1 * NBLD;
    float* Cf   = ws + 2 * NBLD;
    float* Sl   = ws + 3 * NBLD;
    float* qf   = ws + 4 * NBLD;
    float* kf   = ws + 5 * NBLD;
    float* coff = ws + 6 * NBLD;                        // 16*17*64 floats
    float* csum = coff + (size_t)BB * HH * 17 * DHD;    // 256*64 floats

    gemm3_act_v2<<<768, 256, 0, stream>>>(x, Wa, ba, Wb, bb, Wc, bc, logA, Bf, Cf);
    chunk_sums256<<<BB * HH * NCC, 256, 0, stream>>>(logA, csum);
    scan256<<<BB * HH * NCC, 256, 0, stream>>>(logA, Bf, Cf, csum, Sl, qf, kf, coff);
    zero_upper<<<BB * HH * 120, 256, 0, stream>>>(out);
    offdiag_kernel<<<BB * HH * 120, 256, 0, stream>>>(qf, kf, coff, out);
    diag_kernel<<<BB * HH * NCC, 256, 0, stream>>>(Sl, Bf, Cf, out);
}

// Round 3
// 102.559 us; speedup vs baseline: 1.5302x; 1.2987x over previous
//
#include <hip/hip_runtime.h>
#include <math.h>

#define BB 2
#define LL 1024
#define DD 512
#define HH 8
#define DHD 64
#define QQ 64
#define NCC 16

typedef __attribute__((ext_vector_type(8))) short s8b;   // 8 bf16 (4 VGPRs)
typedef __attribute__((ext_vector_type(4))) float f4;    // 4 fp32 acc

__device__ __forceinline__ void gld16(const void* g, void* l) {
    __builtin_amdgcn_global_load_lds(
        (const __attribute__((address_space(1))) unsigned int*)g,
        (__attribute__((address_space(3))) unsigned int*)l, 16, 0, 0);
}

__device__ __forceinline__ void bf16split(float f, unsigned short& h, unsigned short& l) {
    unsigned u  = __float_as_uint(f);
    unsigned hb = (u + 0x7FFFu + ((u >> 16) & 1u)) & 0xFFFF0000u;   // RTNE bf16
    float fh = __uint_as_float(hb);
    float fl = f - fh;
    unsigned ul = __float_as_uint(fl);
    unsigned lb = (ul + 0x7FFFu + ((ul >> 16) & 1u)) >> 16;
    h = (unsigned short)(hb >> 16);
    l = (unsigned short)lb;
}

// ---------------------------------------------------------------------------
// Kernel 0: split x / Wa / Wb / Wc into bf16 hi/lo arrays.
// 262144 float4-groups of x + 196608 of W = 458752 = 1792 blocks x 256.
// ---------------------------------------------------------------------------
__global__ __launch_bounds__(256) void convert_split(
    const float* __restrict__ x, const float* __restrict__ Wa,
    const float* __restrict__ Wb, const float* __restrict__ Wc,
    unsigned short* __restrict__ xh, unsigned short* __restrict__ xl,
    unsigned short* __restrict__ wh, unsigned short* __restrict__ wl)
{
    const int g = blockIdx.x * 256 + threadIdx.x;    // float4 index
    const float* src;
    unsigned short *dh, *dl;
    if (g < 262144) {
        const size_t off = (size_t)g * 4;
        src = x + off; dh = xh + off; dl = xl + off;
    } else {
        const size_t j = (size_t)(g - 262144) * 4;   // 0..786431
        const int wsel = (int)(j >> 18);             // 262144 elements each
        const size_t r = j & 262143;
        src = (wsel == 0 ? Wa : (wsel == 1 ? Wb : Wc)) + r;
        dh = wh + j; dl = wl + j;
    }
    const float4 v = *(const float4*)src;
    const float f[4] = {v.x, v.y, v.z, v.w};
    unsigned short h[4], l[4];
    #pragma unroll
    for (int i = 0; i < 4; ++i) bf16split(f[i], h[i], l[i]);
    *(uint2*)dh = make_uint2((unsigned)h[0] | ((unsigned)h[1] << 16),
                             (unsigned)h[2] | ((unsigned)h[3] << 16));
    *(uint2*)dl = make_uint2((unsigned)l[0] | ((unsigned)l[1] << 16),
                             (unsigned)l[2] | ((unsigned)l[3] << 16));
}

// ---------------------------------------------------------------------------
// Kernel 1: MFMA GEMM  out = x @ W^T + b  via split-bf16 (hh + hl + lh).
// 64x64 tile, 256 thr = 4 waves in 2x2 of 32x32; mfma_f32_16x16x32_bf16.
// LDS [4 kslots][64 rows][8 bf16] per tile (xh,xl,wh,wl) = 16 KB.
// blockIdx>>8 selects weight; wsel==0 applies logsigmoid.
// ---------------------------------------------------------------------------
__global__ __launch_bounds__(256) void gemm3_mfma(
    const unsigned short* __restrict__ xh, const unsigned short* __restrict__ xl,
    const unsigned short* __restrict__ wh, const unsigned short* __restrict__ wl,
    const float* __restrict__ ba, const float* __restrict__ bb, const float* __restrict__ bc,
    float* __restrict__ logA, float* __restrict__ Bf, float* __restrict__ Cf)
{
    __shared__ unsigned char lds[16384];
    unsigned char* const l_xh = lds;
    unsigned char* const l_xl = lds + 4096;
    unsigned char* const l_wh = lds + 8192;
    unsigned char* const l_wl = lds + 12288;

    const int wsel = blockIdx.x >> 8;
    const int tile = blockIdx.x & 255;
    const int m0 = (tile >> 3) << 6;     // 32 M-tiles
    const int o0 = (tile & 7) << 6;      // 8 N-tiles
    const int t  = threadIdx.x;
    const int wv = t >> 6;               // wave 0..3
    const int ln = t & 63;
    const int l15 = ln & 15;
    const int l4  = ln >> 4;             // k-group 0..3
    const int wr = (wv >> 1) << 5;       // wave row 0/32
    const int wc = (wv & 1) << 5;        // wave col 0/32

    const unsigned short* __restrict__ whp = wh + (size_t)wsel * 262144;
    const unsigned short* __restrict__ wlp = wl + (size_t)wsel * 262144;

    const size_t gx = (size_t)(m0 + ln) * DD;   // staging row for x tiles
    const size_t gw = (size_t)(o0 + ln) * DD;   // staging row for W tiles
    const int skc = wv * 8;                     // staging k-chunk
    const int sofs = wv * 1024;                 // wave-uniform LDS stage base

    f4 acc[2][2] = {};

    for (int kt = 0; kt < DD; kt += 32) {
        gld16(&xh [gx + kt + skc], l_xh + sofs);
        gld16(&xl [gx + kt + skc], l_xl + sofs);
        gld16(&whp[gw + kt + skc], l_wh + sofs);
        gld16(&wlp[gw + kt + skc], l_wl + sofs);
        __syncthreads();

        const int ka = l4 * 1024;
        const s8b ah0 = *(const s8b*)(l_xh + ka + (wr      + l15) * 16);
        const s8b ah1 = *(const s8b*)(l_xh + ka + (wr + 16 + l15) * 16);
        const s8b al0 = *(const s8b*)(l_xl + ka + (wr      + l15) * 16);
        const s8b al1 = *(const s8b*)(l_xl + ka + (wr + 16 + l15) * 16);
        const s8b bh0 = *(const s8b*)(l_wh + ka + (wc      + l15) * 16);
        const s8b bh1 = *(const s8b*)(l_wh + ka + (wc + 16 + l15) * 16);
        const s8b bl0 = *(const s8b*)(l_wl + ka + (wc      + l15) * 16);
        const s8b bl1 = *(const s8b*)(l_wl + ka + (wc + 16 + l15) * 16);

        acc[0][0] = __builtin_amdgcn_mfma_f32_16x16x32_bf16(ah0, bh0, acc[0][0], 0, 0, 0);
        acc[0][1] = __builtin_amdgcn_mfma_f32_16x16x32_bf16(ah0, bh1, acc[0][1], 0, 0, 0);
        acc[1][0] = __builtin_amdgcn_mfma_f32_16x16x32_bf16(ah1, bh0, acc[1][0], 0, 0, 0);
        acc[1][1] = __builtin_amdgcn_mfma_f32_16x16x32_bf16(ah1, bh1, acc[1][1], 0, 0, 0);
        acc[0][0] = __builtin_amdgcn_mfma_f32_16x16x32_bf16(ah0, bl0, acc[0][0], 0, 0, 0);
        acc[0][1] = __builtin_amdgcn_mfma_f32_16x16x32_bf16(ah0, bl1, acc[0][1], 0, 0, 0);
        acc[1][0] = __builtin_amdgcn_mfma_f32_16x16x32_bf16(ah1, bl0, acc[1][0], 0, 0, 0);
        acc[1][1] = __builtin_amdgcn_mfma_f32_16x16x32_bf16(ah1, bl1, acc[1][1], 0, 0, 0);
        acc[0][0] = __builtin_amdgcn_mfma_f32_16x16x32_bf16(al0, bh0, acc[0][0], 0, 0, 0);
        acc[0][1] = __builtin_amdgcn_mfma_f32_16x16x32_bf16(al0, bh1, acc[0][1], 0, 0, 0);
        acc[1][0] = __builtin_amdgcn_mfma_f32_16x16x32_bf16(al1, bh0, acc[1][0], 0, 0, 0);
        acc[1][1] = __builtin_amdgcn_mfma_f32_16x16x32_bf16(al1, bh1, acc[1][1], 0, 0, 0);
        __syncthreads();
    }

    const float* __restrict__ bias = (wsel == 0) ? ba : ((wsel == 1) ? bb : bc);
    float* __restrict__ dst = (wsel == 0) ? logA : ((wsel == 1) ? Bf : Cf);
    #pragma unroll
    for (int ns = 0; ns < 2; ++ns) {
        const int col = o0 + wc + ns * 16 + l15;
        const float bv = bias[col];
        #pragma unroll
        for (int ms = 0; ms < 2; ++ms) {
            const int rbase = m0 + wr + ms * 16 + l4 * 4;
            #pragma unroll
            for (int r = 0; r < 4; ++r) {
                float v = acc[ms][ns][r] + bv;
                if (wsel == 0)
                    v = fminf(v, 0.f) - log1pf(__expf(-fabsf(v)));  // logsigmoid
                dst[(size_t)(rbase + r) * DD + col] = v;
            }
        }
    }
}

// ---------------------------------------------------------------------------
// Kernel 2a: per-chunk sums of logA. block=(bh,c), 256 thr: wave w sums 16 rows.
// ---------------------------------------------------------------------------
__global__ __launch_bounds__(256) void chunk_sums256(
    const float* __restrict__ logA, float* __restrict__ csum)
{
    __shared__ float part[4][DHD];
    const int blk = blockIdx.x;       // bh*16 + c
    const int bh = blk >> 4, c = blk & 15;
    const int b = bh >> 3, h = bh & 7;
    const int t = threadIdx.x;
    const int d = t & 63, w = t >> 6;
    const size_t base = (size_t)(b * LL + c * QQ + w * 16) * DD + h * DHD + d;
    float s = 0.f;
    #pragma unroll 4
    for (int i = 0; i < 16; ++i) s += logA[base + (size_t)i * DD];
    part[w][d] = s;
    __syncthreads();
    if (t < DHD)
        csum[(size_t)blk * DHD + t] = part[0][t] + part[1][t] + part[2][t] + part[3][t];
}

// ---------------------------------------------------------------------------
// Kernel 2b: scan. block=(bh,c), 256 thr = 4 waves x 16 rows each.
// ---------------------------------------------------------------------------
__global__ __launch_bounds__(256) void scan256(
    const float* __restrict__ logA, const float* __restrict__ Bf,
    const float* __restrict__ Cf, const float* __restrict__ csum,
    float* __restrict__ Sloc, float* __restrict__ qf, float* __restrict__ kf,
    float* __restrict__ coff)
{
    __shared__ float part[4][DHD];
    const int blk = blockIdx.x;
    const int bh = blk >> 4, c = blk & 15;
    const int b = bh >> 3, h = bh & 7;
    const int t = threadIdx.x;
    const int d = t & 63, w = t >> 6;

    const size_t gbase = (size_t)(b * LL + c * QQ + w * 16) * DD + h * DHD + d;
    float ps = 0.f;
    #pragma unroll 4
    for (int i = 0; i < 16; ++i) ps += logA[gbase + (size_t)i * DD];
    part[w][d] = ps;
    __syncthreads();

    const size_t cs0 = ((size_t)bh << 4) * DHD + d;
    float off = 0.f;
    for (int cc = 0; cc < c; ++cc) off += csum[cs0 + (size_t)cc * DHD];
    const float tot = part[0][d] + part[1][d] + part[2][d] + part[3][d];
    if (t < DHD) {
        coff[((size_t)bh * 17 + c) * DHD + t] = off;
        if (c == NCC - 1) coff[((size_t)bh * 17 + 16) * DHD + t] = off + tot;
    }

    float run = 0.f;
    for (int ww = 0; ww < 4; ++ww) if (ww < w) run += part[ww][d];

    const size_t hbase = ((size_t)bh * LL + c * QQ + w * 16) * DHD + d;
    #pragma unroll 4
    for (int i = 0; i < 16; ++i) {
        const size_t gi = gbase + (size_t)i * DD;
        const float la = logA[gi];
        const float cv = Cf[gi];
        const float bv = Bf[gi];
        qf[hbase + (size_t)i * DHD] = cv * __expf(run);       // exp(Sm1 - Eprev)
        run += la;
        Sloc[hbase + (size_t)i * DHD] = run;
        kf[hbase + (size_t)i * DHD] = bv * __expf(tot - run); // exp(E - S)
    }
}

// ---------------------------------------------------------------------------
// Kernel 3a: zero-fill of strict-upper 64x64 tiles. 16 bh x 120 tiles.
// ---------------------------------------------------------------------------
__global__ __launch_bounds__(256) void zero_upper(float* __restrict__ out)
{
    const int bid = blockIdx.x;
    const int bh = bid / 120;
    const int idx = bid - bh * 120;
    int a = (int)((1.0f + sqrtf(1.0f + 8.0f * (float)idx)) * 0.5f);
    if (a * (a - 1) / 2 > idx) --a;
    else if ((a + 1) * a / 2 <= idx) ++a;
    const int m = idx - a * (a - 1) / 2;
    const int n = a;                   // n > m

    const size_t base = ((size_t)bh * LL + (size_t)m * QQ) * LL + (size_t)n * QQ;
    const int t = threadIdx.x;
    const float4 z = make_float4(0.f, 0.f, 0.f, 0.f);
    #pragma unroll
    for (int j = 0; j < 4; ++j) {
        const int f = t + (j << 8);
        const int row = f >> 4;
        const int col = (f & 15) << 2;
        *(float4*)&out[base + (size_t)row * LL + col] = z;
    }
}

// ---------------------------------------------------------------------------
// Kernel 3b: off-diagonal tiles: qf_m @ diag(exp(coff[m]-coff[n+1])) @ kf_n^T.
// ---------------------------------------------------------------------------
__global__ __launch_bounds__(256) void offdiag_kernel(
    const float* __restrict__ qf, const float* __restrict__ kf,
    const float* __restrict__ coff, float* __restrict__ out)
{
    __shared__ float smA[DHD][65];
    __shared__ float smB[DHD][65];
    __shared__ float dv[DHD];

    const int bid = blockIdx.x;
    const int bh = bid / 120;
    const int idx = bid - bh * 120;
    int m = (int)((1.0f + sqrtf(1.0f + 8.0f * (float)idx)) * 0.5f);
    if (m * (m - 1) / 2 > idx) --m;
    else if ((m + 1) * m / 2 <= idx) ++m;
    const int n = idx - m * (m - 1) / 2;   // n < m

    const int t = threadIdx.x;
    const int q0 = ((t >> 4) & 15) << 2;
    const int k0 = (t & 15) << 2;
    const int r  = t >> 4;
    const int dg = (t & 15) << 2;

    if (t < DHD) {
        const size_t cb = (size_t)bh * 17 * DHD + t;
        dv[t] = __expf(coff[cb + (size_t)m * DHD] - coff[cb + (size_t)(n + 1) * DHD]);
    }
    __syncthreads();

    const size_t qb = ((size_t)bh * LL + (size_t)m * QQ) * DHD;
    const size_t kb = ((size_t)bh * LL + (size_t)n * QQ) * DHD;
    const float4 sv = *(const float4*)&dv[dg];
    #pragma unroll
    for (int rr = 0; rr < 64; rr += 16) {
        const int row = r + rr;
        float4 v = *(const float4*)&qf[qb + (size_t)row * DHD + dg];
        smA[dg+0][row] = v.x; smA[dg+1][row] = v.y; smA[dg+2][row] = v.z; smA[dg+3][row] = v.w;
        float4 w = *(const float4*)&kf[kb + (size_t)row * DHD + dg];
        smB[dg+0][row] = w.x*sv.x; smB[dg+1][row] = w.y*sv.y; smB[dg+2][row] = w.z*sv.z; smB[dg+3][row] = w.w*sv.w;
    }
    __syncthreads();

    float acc[4][4] = {};
    #pragma unroll 4
    for (int d = 0; d < DHD; ++d) {
        const float4 av = *(const float4*)&smA[d][q0];
        const float4 bv = *(const float4*)&smB[d][k0];
        acc[0][0] += av.x*bv.x; acc[0][1] += av.x*bv.y; acc[0][2] += av.x*bv.z; acc[0][3] += av.x*bv.w;
        acc[1][0] += av.y*bv.x; acc[1][1] += av.y*bv.y; acc[1][2] += av.y*bv.z; acc[1][3] += av.y*bv.w;
        acc[2][0] += av.z*bv.x; acc[2][1] += av.z*bv.y; acc[2][2] += av.z*bv.z; acc[2][3] += av.z*bv.w;
        acc[3][0] += av.w*bv.x; acc[3][1] += av.w*bv.y; acc[3][2] += av.w*bv.z; acc[3][3] += av.w*bv.w;
    }

    const size_t outrow0 = ((size_t)bh * LL + (size_t)m * QQ) * LL + (size_t)n * QQ;
    #pragma unroll
    for (int i = 0; i < 4; ++i)
        *(float4*)&out[outrow0 + (size_t)(q0 + i) * LL + k0] =
            make_float4(acc[i][0], acc[i][1], acc[i][2], acc[i][3]);
}

// ---------------------------------------------------------------------------
// Kernel 3c: diagonal tiles: masked elementwise  C_q exp(Sloc_{q-1}-Sloc_k) B_k.
// ---------------------------------------------------------------------------
__global__ __launch_bounds__(256) void diag_kernel(
    const float* __restrict__ Sloc, const float* __restrict__ Bf,
    const float* __restrict__ Cf, float* __restrict__ out)
{
    __shared__ float smA[DHD][65];
    __shared__ float smB[DHD][65];
    __shared__ float smC[DHD][65];

    const int blk = blockIdx.x;      // bh*16 + m
    const int bh = blk >> 4, m = blk & 15;
    const int b = bh >> 3, h = bh & 7;
    const int t = threadIdx.x;
    const int q0 = ((t >> 4) & 15) << 2;
    const int k0 = (t & 15) << 2;
    const int r  = t >> 4;
    const int dg = (t & 15) << 2;

    const size_t ab = (size_t)(b * LL + m * QQ) * DD + h * DHD;
    const size_t sb = ((size_t)bh * LL + (size_t)m * QQ) * DHD;
    #pragma unroll
    for (int rr = 0; rr < 64; rr += 16) {
        const int row = r + rr;
        float4 cv = *(const float4*)&Cf[ab + (size_t)row * DD + dg];
        smA[dg+0][row] = cv.x; smA[dg+1][row] = cv.y; smA[dg+2][row] = cv.z; smA[dg+3][row] = cv.w;
        float4 bv = *(const float4*)&Bf[ab + (size_t)row * DD + dg];
        smB[dg+0][row] = bv.x; smB[dg+1][row] = bv.y; smB[dg+2][row] = bv.z; smB[dg+3][row] = bv.w;
        float4 sv = *(const float4*)&Sloc[sb + (size_t)row * DHD + dg];
        smC[dg+0][row] = sv.x; smC[dg+1][row] = sv.y; smC[dg+2][row] = sv.z; smC[dg+3][row] = sv.w;
    }
    __syncthreads();

    float acc[4][4] = {};
    if (q0 + 3 >= k0) {
        #pragma unroll 2
        for (int d = 0; d < DHD; ++d) {
            const float4 cq = *(const float4*)&smA[d][q0];
            const float4 bk = *(const float4*)&smB[d][k0];
            const float4 sk = *(const float4*)&smC[d][k0];
            const float cqa[4] = {cq.x, cq.y, cq.z, cq.w};
            const float bka[4] = {bk.x, bk.y, bk.z, bk.w};
            const float ska[4] = {sk.x, sk.y, sk.z, sk.w};
            float s1a[4];
            #pragma unroll
            for (int i = 0; i < 4; ++i) {
                const int qi = q0 + i;
                s1a[i] = (qi == 0) ? 0.f : smC[d][qi - 1];
            }
            #pragma unroll
            for (int i = 0; i < 4; ++i) {
                #pragma unroll
                for (int j = 0; j < 4; ++j) {
                    const int qi = q0 + i, kj = k0 + j;
                    const float wgt = (qi > kj) ? __expf(s1a[i] - ska[j])
                                                : ((qi == kj) ? 1.f : 0.f);
                    acc[i][j] += cqa[i] * wgt * bka[j];
                }
            }
        }
    }
    const size_t outrow0 = ((size_t)bh * LL + (size_t)m * QQ) * LL + (size_t)m * QQ;
    #pragma unroll
    for (int i = 0; i < 4; ++i)
        *(float4*)&out[outrow0 + (size_t)(q0 + i) * LL + k0] =
            make_float4(acc[i][0], acc[i][1], acc[i][2], acc[i][3]);
}

// ---------------------------------------------------------------------------
extern "C" void kernel_launch(void* const* d_in, const int* in_sizes, int n_in,
                              void* d_out, int out_size, void* d_ws, size_t ws_size,
                              hipStream_t stream) {
    const float* x  = (const float*)d_in[0];
    const float* Wa = (const float*)d_in[1];
    const float* ba = (const float*)d_in[2];
    const float* Wb = (const float*)d_in[3];
    const float* bb = (const float*)d_in[4];
    const float* Wc = (const float*)d_in[5];
    const float* bc = (const float*)d_in[6];
    float* out = (float*)d_out;
    float* ws  = (float*)d_ws;

    const size_t NBLD = (size_t)BB * LL * DD;   // 1,048,576 floats
    float* logA = ws;
    float* Bf   = ws + 1 * NBLD;
    float* Cf   = ws + 2 * NBLD;
    float* Sl   = ws + 3 * NBLD;
    float* qf   = ws + 4 * NBLD;
    float* kf   = ws + 5 * NBLD;
    float* coff = ws + 6 * NBLD;                        // 16*17*64 floats
    float* csum = coff + (size_t)BB * HH * 17 * DHD;    // 256*64 floats

    // bf16 split arrays live in the Sl/qf/kf region: they are fully consumed
    // by gemm3_mfma BEFORE scan256 overwrites that region (stream-ordered).
    unsigned short* xh  = (unsigned short*)(ws + 3 * NBLD);
    unsigned short* xl  = xh + 1048576;
    unsigned short* whp = xl + 1048576;    // 3 x 262144
    unsigned short* wlp = whp + 786432;

    convert_split<<<1792, 256, 0, stream>>>(x, Wa, Wb, Wc, xh, xl, whp, wlp);
    gemm3_mfma<<<768, 256, 0, stream>>>(xh, xl, whp, wlp, ba, bb, bc, logA, Bf, Cf);
    chunk_sums256<<<BB * HH * NCC, 256, 0, stream>>>(logA, csum);
    scan256<<<BB * HH * NCC, 256, 0, stream>>>(logA, Bf, Cf, csum, Sl, qf, kf, coff);
    zero_upper<<<BB * HH * 120, 256, 0, stream>>>(out);
    offdiag_kernel<<<BB * HH * 120, 256, 0, stream>>>(qf, kf, coff, out);
    diag_kernel<<<BB * HH * NCC, 256, 0, stream>>>(Sl, Bf, Cf, out);
}